// Round 1
// baseline (79.702 us; speedup 1.0000x reference)
//
#include <hip/hip_runtime.h>
#include <hip/hip_bf16.h>
#include <stdint.h>

#define IN_DIM  1024
#define LOW     128
#define OUT_DIM 1024
#define BATCH   8
#define SEQ     2048

typedef unsigned short u16;
typedef short bf16x8 __attribute__((ext_vector_type(8)));
typedef unsigned short u16x4 __attribute__((ext_vector_type(4)));
typedef float f32x4 __attribute__((ext_vector_type(4)));

__device__ __forceinline__ u16 f2bf(float f) {
    union { float f; uint32_t u; } v;
    v.f = f;
    uint32_t u = v.u;
    return (u16)((u + 0x7fffu + ((u >> 16) & 1u)) >> 16);
}

// ---------------------------------------------------------------------------
// gen_d: DgT[b][l][d] = sum_kk D_matrix[d*128+l][kk] * k[b][kk]   (bf16 out)
// block: 256 threads covers d in [d0,d0+32), l in [l0,l0+8)
// ---------------------------------------------------------------------------
__global__ __launch_bounds__(256) void gen_d(const float* __restrict__ Dm,
                                             const float* __restrict__ kv,
                                             u16* __restrict__ DgT) {
    __shared__ float ks[BATCH * LOW];        // 4 KB
    __shared__ u16 tb[BATCH * 8 * 32];       // 4 KB transpose buffer
    int t = threadIdx.x;
    ((float4*)ks)[t] = ((const float4*)kv)[t];   // 256*4 = 1024 floats
    __syncthreads();

    int bid = blockIdx.x;
    int d0 = (bid >> 4) * 32;
    int l0 = (bid & 15) * 8;
    int dd = t >> 3, ll = t & 7;
    int p = (d0 + dd) * LOW + (l0 + ll);
    const float4* row = (const float4*)(Dm + (size_t)p * LOW);

    float acc[BATCH];
#pragma unroll
    for (int b = 0; b < BATCH; ++b) acc[b] = 0.f;
#pragma unroll 4
    for (int j = 0; j < 32; ++j) {
        float4 a = row[j];
#pragma unroll
        for (int b = 0; b < BATCH; ++b) {
            const float* kb = ks + b * LOW + j * 4;
            acc[b] += a.x * kb[0] + a.y * kb[1] + a.z * kb[2] + a.w * kb[3];
        }
    }
#pragma unroll
    for (int b = 0; b < BATCH; ++b)
        tb[(b * 8 + ll) * 32 + dd] = f2bf(acc[b]);
    __syncthreads();

    // coalesced write: 64 chunks (b,l') x 64B (32 d)
    int chunk = t >> 2, q = t & 3;
    int b = chunk >> 3, lp = chunk & 7;
    bf16x8 v = *(const bf16x8*)(tb + (b * 8 + lp) * 32 + q * 8);
    *(bf16x8*)(DgT + ((size_t)(b * LOW + l0 + lp) * IN_DIM + d0 + q * 8)) = v;
}

// ---------------------------------------------------------------------------
// gen_u: UgT[b][o][l] = sum_kk U_matrix[l*1024+o][kk] * k[b][kk]   (bf16 out)
// block: 256 threads covers o in [o0,o0+2), l in [0,128)
// ---------------------------------------------------------------------------
__global__ __launch_bounds__(256) void gen_u(const float* __restrict__ Um,
                                             const float* __restrict__ kv,
                                             u16* __restrict__ UgT) {
    __shared__ float ks[BATCH * LOW];
    __shared__ u16 tb[BATCH * 2 * 128];      // 4 KB
    int t = threadIdx.x;
    ((float4*)ks)[t] = ((const float4*)kv)[t];
    __syncthreads();

    int o0 = blockIdx.x * 2;
    int l = t >> 1, oo = t & 1;
    size_t p = (size_t)l * OUT_DIM + (o0 + oo);
    const float4* row = (const float4*)(Um + p * LOW);

    float acc[BATCH];
#pragma unroll
    for (int b = 0; b < BATCH; ++b) acc[b] = 0.f;
#pragma unroll 4
    for (int j = 0; j < 32; ++j) {
        float4 a = row[j];
#pragma unroll
        for (int b = 0; b < BATCH; ++b) {
            const float* kb = ks + b * LOW + j * 4;
            acc[b] += a.x * kb[0] + a.y * kb[1] + a.z * kb[2] + a.w * kb[3];
        }
    }
#pragma unroll
    for (int b = 0; b < BATCH; ++b)
        tb[(b * 2 + oo) * 128 + l] = f2bf(acc[b]);
    __syncthreads();

    // coalesced write: 16 chunks (b,o') x 256B (128 l)
    int chunk = t >> 4, q = t & 15;
    int b = chunk >> 1, op = chunk & 1;
    bf16x8 v = *(const bf16x8*)(tb + (b * 2 + op) * 128 + q * 8);
    *(bf16x8*)(UgT + ((size_t)(b * OUT_DIM + o0 + op) * LOW + q * 8)) = v;
}

// ---------------------------------------------------------------------------
// fc1: h[b][s][l] = relu( sum_d x[b][s][d] * D[b][d][l] )  -> bf16
// tile: M=64 (s), N=128 (all l), K-loop over 1024 step 64. grid = 8*32 = 256
// 4 waves as 2x2; wave computes 32x64 (2x4 16x16 frags)
// ---------------------------------------------------------------------------
__global__ __launch_bounds__(256) void fc1(const float* __restrict__ x,
                                           const u16* __restrict__ DgT,
                                           u16* __restrict__ h) {
    __shared__ u16 As[64][72];    // +8 pad: 144B row stride -> 2-way (free)
    __shared__ u16 Bs[128][72];
    int t = threadIdx.x;
    int bid = blockIdx.x;
    int b = bid >> 5, st = bid & 31;
    int s0 = st * 64;
    const float* xb = x + ((size_t)b * SEQ + s0) * IN_DIM;
    const u16* Db = DgT + (size_t)b * LOW * IN_DIM;

    int w = t >> 6, lane = t & 63;
    int wm = w >> 1, wn = w & 1;
    int lr = lane & 15, lk = (lane >> 4) * 8;

    f32x4 acc[2][4];
#pragma unroll
    for (int mf = 0; mf < 2; ++mf)
#pragma unroll
        for (int nf = 0; nf < 4; ++nf)
            acc[mf][nf] = (f32x4){0.f, 0.f, 0.f, 0.f};

    int ar = t >> 2, ac = t & 3;   // A staging: 4 threads/row
    int br = t >> 1, bh = t & 1;   // B staging: 2 threads/row

    for (int kt = 0; kt < IN_DIM / 64; ++kt) {
        int k0 = kt * 64;
        // stage A: x f32 -> bf16, 64x64
#pragma unroll
        for (int i = 0; i < 4; ++i) {
            float4 v = *(const float4*)(xb + (size_t)ar * IN_DIM + k0 + (ac + 4 * i) * 4);
            u16x4 o;
            o.x = f2bf(v.x); o.y = f2bf(v.y); o.z = f2bf(v.z); o.w = f2bf(v.w);
            *(u16x4*)(&As[ar][(ac + 4 * i) * 4]) = o;
        }
        // stage B: DgT bf16, 128x64
#pragma unroll
        for (int i = 0; i < 4; ++i) {
            bf16x8 v = *(const bf16x8*)(Db + (size_t)br * IN_DIM + k0 + bh * 32 + i * 8);
            *(bf16x8*)(&Bs[br][bh * 32 + i * 8]) = v;
        }
        __syncthreads();
#pragma unroll
        for (int ks = 0; ks < 2; ++ks) {
            int kk = ks * 32 + lk;
            bf16x8 af[2], bfr[4];
#pragma unroll
            for (int mf = 0; mf < 2; ++mf)
                af[mf] = *(const bf16x8*)(&As[wm * 32 + mf * 16 + lr][kk]);
#pragma unroll
            for (int nf = 0; nf < 4; ++nf)
                bfr[nf] = *(const bf16x8*)(&Bs[wn * 64 + nf * 16 + lr][kk]);
#pragma unroll
            for (int mf = 0; mf < 2; ++mf)
#pragma unroll
                for (int nf = 0; nf < 4; ++nf)
                    acc[mf][nf] = __builtin_amdgcn_mfma_f32_16x16x32_bf16(
                        af[mf], bfr[nf], acc[mf][nf], 0, 0, 0);
        }
        __syncthreads();
    }
    // epilogue: relu -> bf16
    u16* hb = h + ((size_t)b * SEQ + s0) * LOW;
#pragma unroll
    for (int mf = 0; mf < 2; ++mf)
#pragma unroll
        for (int nf = 0; nf < 4; ++nf) {
            int col = wn * 64 + nf * 16 + lr;
#pragma unroll
            for (int j = 0; j < 4; ++j) {
                int rrow = wm * 32 + mf * 16 + (lane >> 4) * 4 + j;
                hb[(size_t)rrow * LOW + col] = f2bf(fmaxf(acc[mf][nf][j], 0.f));
            }
        }
}

// ---------------------------------------------------------------------------
// fc2: out[b][s][o] = sum_l h[b][s][l] * U[b][l][o]   (f32 out)
// tile: 128x128, K=128 staged once. grid = 8*16*8 = 1024
// 64KB LDS, XOR-swizzled (16B chunk ^ row&7) for conflict-free ds_read_b128
// ---------------------------------------------------------------------------
__global__ __launch_bounds__(256) void fc2(const u16* __restrict__ h,
                                           const u16* __restrict__ UgT,
                                           float* __restrict__ out) {
    __shared__ u16 As[128 * 128];   // 32 KB
    __shared__ u16 Bs[128 * 128];   // 32 KB
    int t = threadIdx.x;
    int bid = blockIdx.x;
    int b = bid >> 7, st = (bid >> 3) & 15, ot = bid & 7;
    int s0 = st * 128, o0 = ot * 128;
    const u16* hb = h + ((size_t)b * SEQ + s0) * LOW;    // contiguous 32KB
    const u16* Ub = UgT + ((size_t)b * OUT_DIM + o0) * LOW; // contiguous 32KB

    // stage both tiles, perfectly coalesced flat 16B chunks, swizzled LDS dest
#pragma unroll
    for (int i = 0; i < 8; ++i) {
        int ch = i * 256 + t;          // chunk id, 2048 total
        int row = ch >> 4, c = ch & 15;
        int sw = c ^ (row & 7);
        *(bf16x8*)(As + row * 128 + sw * 8) = *(const bf16x8*)(hb + (size_t)ch * 8);
        *(bf16x8*)(Bs + row * 128 + sw * 8) = *(const bf16x8*)(Ub + (size_t)ch * 8);
    }
    __syncthreads();

    int w = t >> 6, lane = t & 63;
    int wm = w >> 1, wn = w & 1;
    int lr = lane & 15, lkc = (lane >> 4);   // k-chunk part

    f32x4 acc[4][4];
#pragma unroll
    for (int mf = 0; mf < 4; ++mf)
#pragma unroll
        for (int nf = 0; nf < 4; ++nf)
            acc[mf][nf] = (f32x4){0.f, 0.f, 0.f, 0.f};

#pragma unroll
    for (int ks = 0; ks < 4; ++ks) {
        bf16x8 af[4], bfr[4];
#pragma unroll
        for (int mf = 0; mf < 4; ++mf) {
            int row = wm * 64 + mf * 16 + lr;
            int sw = (ks * 4 + lkc) ^ (row & 7);
            af[mf] = *(const bf16x8*)(As + row * 128 + sw * 8);
        }
#pragma unroll
        for (int nf = 0; nf < 4; ++nf) {
            int row = wn * 64 + nf * 16 + lr;
            int sw = (ks * 4 + lkc) ^ (row & 7);
            bfr[nf] = *(const bf16x8*)(Bs + row * 128 + sw * 8);
        }
#pragma unroll
        for (int mf = 0; mf < 4; ++mf)
#pragma unroll
            for (int nf = 0; nf < 4; ++nf)
                acc[mf][nf] = __builtin_amdgcn_mfma_f32_16x16x32_bf16(
                    af[mf], bfr[nf], acc[mf][nf], 0, 0, 0);
    }

    float* ob = out + ((size_t)b * SEQ + s0) * OUT_DIM + o0;
#pragma unroll
    for (int mf = 0; mf < 4; ++mf)
#pragma unroll
        for (int nf = 0; nf < 4; ++nf) {
            int col = wn * 64 + nf * 16 + lr;
#pragma unroll
            for (int j = 0; j < 4; ++j) {
                int rrow = wm * 64 + mf * 16 + (lane >> 4) * 4 + j;
                ob[(size_t)rrow * OUT_DIM + col] = acc[mf][nf][j];
            }
        }
}

extern "C" void kernel_launch(void* const* d_in, const int* in_sizes, int n_in,
                              void* d_out, int out_size, void* d_ws, size_t ws_size,
                              hipStream_t stream) {
    const float* x  = (const float*)d_in[0];
    const float* kv = (const float*)d_in[1];
    const float* Dm = (const float*)d_in[2];
    const float* Um = (const float*)d_in[3];
    float* out = (float*)d_out;

    u16* DgT = (u16*)d_ws;                                   // 2 MB
    u16* UgT = DgT + (size_t)BATCH * LOW * IN_DIM;           // 2 MB
    u16* hbuf = UgT + (size_t)BATCH * OUT_DIM * LOW;         // 4 MB

    gen_d<<<dim3(512), dim3(256), 0, stream>>>(Dm, kv, DgT);
    gen_u<<<dim3(512), dim3(256), 0, stream>>>(Um, kv, UgT);
    fc1<<<dim3(256), dim3(256), 0, stream>>>(x, DgT, hbuf);
    fc2<<<dim3(1024), dim3(256), 0, stream>>>(hbuf, UgT, out);
}

// Round 2
// 71.564 us; speedup vs baseline: 1.1137x; 1.1137x over previous
//
#include <hip/hip_runtime.h>
#include <hip/hip_bf16.h>
#include <stdint.h>

#define IN_DIM  1024
#define LOW     128
#define OUT_DIM 1024
#define BATCH   8
#define SEQ     2048

typedef unsigned short u16;
typedef short bf16x8 __attribute__((ext_vector_type(8)));
typedef unsigned short u16x4 __attribute__((ext_vector_type(4)));
typedef float f32x4 __attribute__((ext_vector_type(4)));

__device__ __forceinline__ u16 f2bf(float f) {
    union { float f; uint32_t u; } v;
    v.f = f;
    uint32_t u = v.u;
    return (u16)((u + 0x7fffu + ((u >> 16) & 1u)) >> 16);
}

// ---------------------------------------------------------------------------
// gen_w: unified hyper-weight generation.
//   D half (bid<512):  DgT[b][l][d] = dot(Dm[d*128+l][:], k[b][:])
//   U half (bid>=512): UgT[b][o][l] = dot(Um[l*1024+o][:], k[b][:])
// Both are p = m*NTOT + n with output OUT[b][n][m-run]. Block tile:
// m-tile 32 x n-tile 8 = 256 rows, processed as 16 chunks of 16 rows.
// Stage: coalesced float4 loads -> XOR-swizzled LDS (conflict-free b128 read).
// Compute: thread = (row r 0..15, batch-pair bp 0..3, quarter q 0..3);
// k-vector lives in 16 float4 registers; quad shfl_xor reduce.
// ---------------------------------------------------------------------------
__global__ __launch_bounds__(256) void gen_w(const float* __restrict__ Dm,
                                             const float* __restrict__ Um,
                                             const float* __restrict__ kv,
                                             u16* __restrict__ DgT,
                                             u16* __restrict__ UgT) {
    __shared__ float stage[16 * 128];          // 8 KB staging chunk
    __shared__ u16 tb[BATCH * 8 * 32];         // 4 KB transpose buffer

    int t = threadIdx.x;
    int bid = blockIdx.x;
    bool isU = bid >= 512;
    int rb = isU ? (bid - 512) : bid;
    const float* src = isU ? Um : Dm;
    u16* out = isU ? UgT : DgT;
    int NTOT = isU ? 1024 : 128;   // minor dim total == p row-stride
    int MTOT = isU ? 128 : 1024;   // major dim total (contiguous output run)
    int sh = isU ? 7 : 4;
    int m0 = (rb >> sh) * 32;
    int n0 = (rb & ((1 << sh) - 1)) * 8;

    int r  = t >> 4;          // chunk-local row 0..15
    int bp = (t >> 2) & 3;    // batch pair 0..3
    int q  = t & 3;           // quarter 0..3
    int sw = ((q << 1) ^ (r & 7)) & 7;

    // k slices in registers: batches 2bp, 2bp+1, quarter q (8 float4 each)
    f32x4 kr0[8], kr1[8];
#pragma unroll
    for (int j4 = 0; j4 < 8; ++j4) {
        kr0[j4] = *(const f32x4*)(kv + (2 * bp)     * LOW + q * 32 + j4 * 4);
        kr1[j4] = *(const f32x4*)(kv + (2 * bp + 1) * LOW + q * 32 + j4 * 4);
    }

    for (int ch = 0; ch < 16; ++ch) {
        __syncthreads();   // previous chunk's readers done before overwrite
        // stage 16 rows (8 KB), fully coalesced, swizzled dest
#pragma unroll
        for (int i = 0; i < 2; ++i) {
            int f = t + 256 * i;
            int rs = f >> 5, c = f & 31;
            int qs = c >> 3, j4s = c & 7;
            int cp = (qs << 3) | (j4s ^ (((qs << 1) ^ (rs & 7)) & 7));
            int m = m0 + 2 * ch + (rs >> 3);
            int n = n0 + (rs & 7);
            f32x4 v = *(const f32x4*)(src + ((size_t)m * NTOT + n) * 128 + c * 4);
            *(f32x4*)(stage + rs * 128 + cp * 4) = v;
        }
        __syncthreads();
        float a0 = 0.f, a1 = 0.f;
#pragma unroll
        for (int j4 = 0; j4 < 8; ++j4) {
            f32x4 a = *(const f32x4*)(stage + r * 128 + ((q << 3) | (j4 ^ sw)) * 4);
            a0 += a.x * kr0[j4].x + a.y * kr0[j4].y + a.z * kr0[j4].z + a.w * kr0[j4].w;
            a1 += a.x * kr1[j4].x + a.y * kr1[j4].y + a.z * kr1[j4].z + a.w * kr1[j4].w;
        }
        a0 += __shfl_xor(a0, 1); a0 += __shfl_xor(a0, 2);
        a1 += __shfl_xor(a1, 1); a1 += __shfl_xor(a1, 2);
        if (q == 0) {
            int nn = r & 7, mm = 2 * ch + (r >> 3);
            tb[(2 * bp)     * 256 + nn * 32 + mm] = f2bf(a0);
            tb[(2 * bp + 1) * 256 + nn * 32 + mm] = f2bf(a1);
        }
    }
    __syncthreads();
    // coalesced output: 64 chunks (b, n') x 64B (32 m)
    int c64 = t >> 2, q4 = t & 3;
    int bw = c64 >> 3, np = c64 & 7;
    bf16x8 v = *(const bf16x8*)(tb + bw * 256 + np * 32 + q4 * 8);
    *(bf16x8*)(out + ((size_t)(bw * NTOT + n0 + np)) * MTOT + m0 + q4 * 8) = v;
}

// ---------------------------------------------------------------------------
// fc1: h[b][s][l] = relu( sum_d x[b][s][d] * D[b][d][l] )  -> bf16
// tile: M=32 (s), N=128 (all l), K-loop 1024 step 64. grid = 8*64 = 512
// (2 blocks/CU so barrier drains hide). 4 waves 2x2; wave = 16x64 (acc[4]).
// ---------------------------------------------------------------------------
__global__ __launch_bounds__(256) void fc1(const float* __restrict__ x,
                                           const u16* __restrict__ DgT,
                                           u16* __restrict__ h) {
    __shared__ u16 As[32][72];
    __shared__ u16 Bs[128][72];
    int t = threadIdx.x;
    int bid = blockIdx.x;
    int b = bid >> 6, st = bid & 63;
    int s0 = st * 32;
    const float* xb = x + ((size_t)b * SEQ + s0) * IN_DIM;
    const u16* Db = DgT + (size_t)b * LOW * IN_DIM;

    int w = t >> 6, lane = t & 63;
    int wm = w >> 1, wn = w & 1;
    int lr = lane & 15, hi = lane >> 4;

    f32x4 acc[4];
#pragma unroll
    for (int nf = 0; nf < 4; ++nf) acc[nf] = (f32x4){0.f, 0.f, 0.f, 0.f};

    int ar = t >> 3, ac = t & 7;   // A: 32 rows x 8 threads (128B runs)
    int brt = t >> 3, bc = t & 7;  // B: 32 rows/pass x 8 threads (128B runs)

    for (int kt = 0; kt < IN_DIM / 64; ++kt) {
        int k0 = kt * 64;
        // stage A: x f32 -> bf16, 32x64
#pragma unroll
        for (int i = 0; i < 2; ++i) {
            float4 v = *(const float4*)(xb + (size_t)ar * IN_DIM + k0 + ac * 4 + i * 32);
            u16x4 o;
            o.x = f2bf(v.x); o.y = f2bf(v.y); o.z = f2bf(v.z); o.w = f2bf(v.w);
            *(u16x4*)(&As[ar][ac * 4 + i * 32]) = o;
        }
        // stage B: DgT bf16, 128x64
#pragma unroll
        for (int i = 0; i < 4; ++i) {
            int row = brt + 32 * i;
            bf16x8 v = *(const bf16x8*)(Db + (size_t)row * IN_DIM + k0 + bc * 8);
            *(bf16x8*)(&Bs[row][bc * 8]) = v;
        }
        __syncthreads();
#pragma unroll
        for (int ks = 0; ks < 2; ++ks) {
            int kk = ks * 32 + hi * 8;
            bf16x8 af = *(const bf16x8*)(&As[wm * 16 + lr][kk]);
#pragma unroll
            for (int nf = 0; nf < 4; ++nf) {
                bf16x8 bf = *(const bf16x8*)(&Bs[wn * 64 + nf * 16 + lr][kk]);
                acc[nf] = __builtin_amdgcn_mfma_f32_16x16x32_bf16(af, bf, acc[nf], 0, 0, 0);
            }
        }
        __syncthreads();
    }
    u16* hb = h + ((size_t)b * SEQ + s0) * LOW;
#pragma unroll
    for (int nf = 0; nf < 4; ++nf) {
        int col = wn * 64 + nf * 16 + lr;
#pragma unroll
        for (int j = 0; j < 4; ++j) {
            int rrow = wm * 16 + hi * 4 + j;
            hb[(size_t)rrow * LOW + col] = f2bf(fmaxf(acc[nf][j], 0.f));
        }
    }
}

// ---------------------------------------------------------------------------
// fc2: out[b][s][o] = sum_l h[b][s][l] * U[b][l][o]   (f32 out)
// tile: 128x128, K=128 staged once. grid = 8*16*8 = 1024 (4 blocks/CU)
// 64KB LDS, XOR-swizzled (16B chunk ^ row&7) for conflict-free ds_read_b128
// ---------------------------------------------------------------------------
__global__ __launch_bounds__(256) void fc2(const u16* __restrict__ h,
                                           const u16* __restrict__ UgT,
                                           float* __restrict__ out) {
    __shared__ u16 As[128 * 128];   // 32 KB
    __shared__ u16 Bs[128 * 128];   // 32 KB
    int t = threadIdx.x;
    int bid = blockIdx.x;
    int b = bid >> 7, st = (bid >> 3) & 15, ot = bid & 7;
    int s0 = st * 128, o0 = ot * 128;
    const u16* hb = h + ((size_t)b * SEQ + s0) * LOW;
    const u16* Ub = UgT + ((size_t)b * OUT_DIM + o0) * LOW;

#pragma unroll
    for (int i = 0; i < 8; ++i) {
        int ch = i * 256 + t;
        int row = ch >> 4, c = ch & 15;
        int swc = c ^ (row & 7);
        *(bf16x8*)(As + row * 128 + swc * 8) = *(const bf16x8*)(hb + (size_t)ch * 8);
        *(bf16x8*)(Bs + row * 128 + swc * 8) = *(const bf16x8*)(Ub + (size_t)ch * 8);
    }
    __syncthreads();

    int w = t >> 6, lane = t & 63;
    int wm = w >> 1, wn = w & 1;
    int lr = lane & 15, lkc = (lane >> 4);

    f32x4 acc[4][4];
#pragma unroll
    for (int mf = 0; mf < 4; ++mf)
#pragma unroll
        for (int nf = 0; nf < 4; ++nf)
            acc[mf][nf] = (f32x4){0.f, 0.f, 0.f, 0.f};

#pragma unroll
    for (int ks = 0; ks < 4; ++ks) {
        bf16x8 af[4], bfr[4];
#pragma unroll
        for (int mf = 0; mf < 4; ++mf) {
            int row = wm * 64 + mf * 16 + lr;
            int swc = (ks * 4 + lkc) ^ (row & 7);
            af[mf] = *(const bf16x8*)(As + row * 128 + swc * 8);
        }
#pragma unroll
        for (int nf = 0; nf < 4; ++nf) {
            int row = wn * 64 + nf * 16 + lr;
            int swc = (ks * 4 + lkc) ^ (row & 7);
            bfr[nf] = *(const bf16x8*)(Bs + row * 128 + swc * 8);
        }
#pragma unroll
        for (int mf = 0; mf < 4; ++mf)
#pragma unroll
            for (int nf = 0; nf < 4; ++nf)
                acc[mf][nf] = __builtin_amdgcn_mfma_f32_16x16x32_bf16(
                    af[mf], bfr[nf], acc[mf][nf], 0, 0, 0);
    }

    float* ob = out + ((size_t)b * SEQ + s0) * OUT_DIM + o0;
#pragma unroll
    for (int mf = 0; mf < 4; ++mf)
#pragma unroll
        for (int nf = 0; nf < 4; ++nf) {
            int col = wn * 64 + nf * 16 + lr;
#pragma unroll
            for (int j = 0; j < 4; ++j) {
                int rrow = wm * 64 + mf * 16 + (lane >> 4) * 4 + j;
                ob[(size_t)rrow * OUT_DIM + col] = acc[mf][nf][j];
            }
        }
}

extern "C" void kernel_launch(void* const* d_in, const int* in_sizes, int n_in,
                              void* d_out, int out_size, void* d_ws, size_t ws_size,
                              hipStream_t stream) {
    const float* x  = (const float*)d_in[0];
    const float* kv = (const float*)d_in[1];
    const float* Dm = (const float*)d_in[2];
    const float* Um = (const float*)d_in[3];
    float* out = (float*)d_out;

    u16* DgT = (u16*)d_ws;                                   // 2 MB
    u16* UgT = DgT + (size_t)BATCH * LOW * IN_DIM;           // 2 MB
    u16* hbuf = UgT + (size_t)BATCH * OUT_DIM * LOW;         // 4 MB

    gen_w<<<dim3(1024), dim3(256), 0, stream>>>(Dm, Um, kv, DgT, UgT);
    fc1<<<dim3(512), dim3(256), 0, stream>>>(x, DgT, hbuf);
    fc2<<<dim3(1024), dim3(256), 0, stream>>>(hbuf, UgT, out);
}